// Round 6
// baseline (5428.033 us; speedup 1.0000x reference)
//
#include <hip/hip_runtime.h>
#include <hip/hip_bf16.h>
#include <cstddef>

typedef unsigned short u16;
typedef short bf16x8 __attribute__((ext_vector_type(8)));   // 8 bf16 bit-patterns (4 VGPRs)
typedef float f32x4 __attribute__((ext_vector_type(4)));
typedef unsigned short u16x8 __attribute__((ext_vector_type(8)));
typedef unsigned short u16x4 __attribute__((ext_vector_type(4)));

#define MDIM 16384
#define NDIM 512

__device__ __forceinline__ float b2f(u16 u) {
    return __uint_as_float(((unsigned int)u) << 16);
}
__device__ __forceinline__ u16 f2b(float f) {  // round-to-nearest-even
    unsigned int x = __float_as_uint(f);
    x += 0x7fffu + ((x >> 16) & 1u);
    return (u16)(x >> 16);
}

// C(rows x 512) = A(rows x KDIM) * Bt(512 x KDIM)^T + bias(fp32)
// AF32: A is fp32 (converted to bf16 during staging); else A is bf16.
// EPI 0: +addf (fp32), write Cf fp32 AND Cb bf16   (projection -> state)
// EPI 1: tanh, write Cb bf16                        (hidden layers)
// EPI 2: plain, write Cb bf16                       (k output)
template <int KDIM, int EPI, bool AF32>
__global__ __launch_bounds__(256, 2) void gemm_bt(
    const void* __restrict__ Avoid, const u16* __restrict__ Bt,
    const float* __restrict__ bias, const float* __restrict__ addf,
    u16* __restrict__ Cb, float* __restrict__ Cf) {
    __shared__ u16 As[128 * 72];   // +8 pad breaks ds_read_b128 bank conflicts
    __shared__ u16 Bs[128 * 72];
    const int tid = threadIdx.x;
    const int m0 = blockIdx.y * 128;
    const int n0 = blockIdx.x * 128;
    const int lane = tid & 63;
    const int wave = tid >> 6;
    const int wm = (wave & 1) * 64;
    const int wn = (wave >> 1) * 64;
    const int lr = lane & 15;
    const int lk = (lane >> 4) * 8;

    f32x4 acc[4][4];
    f32x4 zero = {0.0f, 0.0f, 0.0f, 0.0f};
#pragma unroll
    for (int i = 0; i < 4; ++i)
#pragma unroll
        for (int j = 0; j < 4; ++j) acc[i][j] = zero;

    const int r0 = tid >> 3;       // staging row 0..31
    const int c0 = (tid & 7) * 8;  // staging col (8-elem chunks)

    for (int kt = 0; kt < KDIM / 64; ++kt) {
        const int k0 = kt * 64;
#pragma unroll
        for (int it = 0; it < 4; ++it) {
            int r = it * 32 + r0;
            if constexpr (AF32) {
                const float* Af = (const float*)Avoid;
                const float* src = Af + (size_t)(m0 + r) * KDIM + k0 + c0;
                f32x4 lo = *(const f32x4*)(src);
                f32x4 hi = *(const f32x4*)(src + 4);
                u16x8 t;
#pragma unroll
                for (int q = 0; q < 4; ++q) { t[q] = f2b(lo[q]); t[q + 4] = f2b(hi[q]); }
                *(u16x8*)(&As[r * 72 + c0]) = t;
            } else {
                const u16* Ab = (const u16*)Avoid;
                *(f32x4*)(&As[r * 72 + c0]) =
                    *(const f32x4*)(Ab + (size_t)(m0 + r) * KDIM + k0 + c0);
            }
            *(f32x4*)(&Bs[r * 72 + c0]) =
                *(const f32x4*)(Bt + (size_t)(n0 + r) * KDIM + k0 + c0);
        }
        __syncthreads();
#pragma unroll
        for (int kk = 0; kk < 2; ++kk) {
            bf16x8 af[4], bw[4];
#pragma unroll
            for (int i = 0; i < 4; ++i) {
                af[i] = __builtin_bit_cast(
                    bf16x8, *(const f32x4*)(&As[(wm + i * 16 + lr) * 72 + kk * 32 + lk]));
                bw[i] = __builtin_bit_cast(
                    bf16x8, *(const f32x4*)(&Bs[(wn + i * 16 + lr) * 72 + kk * 32 + lk]));
            }
#pragma unroll
            for (int i = 0; i < 4; ++i)
#pragma unroll
                for (int j = 0; j < 4; ++j)
                    acc[i][j] = __builtin_amdgcn_mfma_f32_16x16x32_bf16(
                        af[i], bw[j], acc[i][j], 0, 0, 0);
        }
        __syncthreads();
    }
    // epilogue: C/D layout col=lane&15, row=(lane>>4)*4+reg
    // (probe-verified in R5: bit-identical to self-calibrated mapping)
#pragma unroll
    for (int j = 0; j < 4; ++j) {
        const int col = n0 + wn + j * 16 + lr;
        const float bv = bias[col];
#pragma unroll
        for (int i = 0; i < 4; ++i) {
            const int rowb = m0 + wm + i * 16 + (lane >> 4) * 4;
#pragma unroll
            for (int r = 0; r < 4; ++r) {
                float v = acc[i][j][r] + bv;
                size_t off = (size_t)(rowb + r) * NDIM + col;
                if constexpr (EPI == 0) {
                    v += addf[off];
                    Cf[off] = v;
                    Cb[off] = f2b(v);
                }
                if constexpr (EPI == 1) Cb[off] = f2b(tanhf(v));
                if constexpr (EPI == 2) Cb[off] = f2b(v);
            }
        }
    }
}

// out_bf16[c*R + r] = in_f32[r*Ncols + c]   (weight transpose + cast, tiny)
__global__ void transpose_k(const float* __restrict__ in, u16* __restrict__ out,
                            int R, int Ncols) {
    int idx = blockIdx.x * 256 + threadIdx.x;
    int r = idx / Ncols, c = idx % Ncols;
    out[(size_t)c * R + r] = f2b(in[idx]);
}

// a = S32 + c1*p1 + ... (p's bf16); write outB bf16 (always), outF fp32 (opt)
__global__ __launch_bounds__(256) void combo(
    const float* __restrict__ S32,
    const u16* __restrict__ p1, const u16* __restrict__ p2,
    const u16* __restrict__ p3, const u16* __restrict__ p4,
    const u16* __restrict__ p5,
    float c1, float c2, float c3, float c4, float c5, int nterms,
    float* __restrict__ outF, u16* __restrict__ outB) {
    size_t off = ((size_t)blockIdx.x * 256 + threadIdx.x) * 4;
    f32x4 a = *(const f32x4*)(S32 + off);
    const u16* ps[5] = {p1, p2, p3, p4, p5};
    float cs[5] = {c1, c2, c3, c4, c5};
    for (int t = 0; t < nterms; ++t) {
        u16x4 v = *(const u16x4*)(ps[t] + off);
#pragma unroll
        for (int i = 0; i < 4; ++i) a[i] += cs[t] * b2f(v[i]);
    }
    if (outF) *(f32x4*)(outF + off) = a;
    u16x4 o;
#pragma unroll
    for (int i = 0; i < 4; ++i) o[i] = f2b(a[i]);
    *(u16x4*)(outB + off) = o;
}

extern "C" void kernel_launch(void* const* d_in, const int* in_sizes, int n_in,
                              void* d_out, int out_size, void* d_ws, size_t ws_size,
                              hipStream_t stream) {
    // ---- order-robust input mapping via in_sizes ----
    const float *y = nullptr, *u_t = nullptr, *Wp = nullptr, *bp = nullptr;
    const float *W1 = nullptr, *b1 = nullptr, *W2 = nullptr, *b2 = nullptr;
    const float *W3 = nullptr, *b3 = nullptr;
    {
        const float* w262[3] = {nullptr, nullptr, nullptr};
        const float* s512[4] = {nullptr, nullptr, nullptr, nullptr};
        int i512[4] = {0, 0, 0, 0};
        int n262 = 0, n512 = 0;
        for (int i = 0; i < n_in; ++i) {
            const float* p = (const float*)d_in[i];
            int sz = in_sizes[i];
            if (sz == MDIM * NDIM) y = p;
            else if (sz == MDIM * 256) u_t = p;
            else if (sz == 256 * 512) Wp = p;
            else if (sz == 512 * 512) { if (n262 < 3) w262[n262++] = p; }
            else if (sz == 512) { if (n512 < 4) { i512[n512] = i; s512[n512++] = p; } }
        }
        W1 = w262[0]; W2 = w262[1]; W3 = w262[2];
        bool contig = (n512 == 4) && (i512[3] == i512[0] + 3);
        if (contig) { b1 = s512[0]; b2 = s512[1]; b3 = s512[2]; bp = s512[3]; }
        else        { bp = s512[0]; b1 = s512[1]; b2 = s512[2]; b3 = s512[3]; }
        if (!y || !u_t || !Wp || !W1 || n512 < 4) {  // fallback: dict order
            y  = (const float*)d_in[0]; u_t = (const float*)d_in[1];
            Wp = (const float*)d_in[2]; bp  = (const float*)d_in[3];
            W1 = (const float*)d_in[4]; b1  = (const float*)d_in[5];
            W2 = (const float*)d_in[6]; b2  = (const float*)d_in[7];
            W3 = (const float*)d_in[8]; b3  = (const float*)d_in[9];
        }
    }

    u16* ws  = (u16*)d_ws;
    u16* Wpt = ws;                    // 512x256 bf16  (N x K, K contiguous)
    u16* W1t = Wpt + 512 * 256;       // 512x512 bf16
    u16* W2t = W1t + 512 * 512;
    u16* W3t = W2t + 512 * 512;
    const size_t wfix = 512 * 256 + 3 * 512 * 512;   // 917504 u16 = 1.84 MB

    // adaptive chunking: per row 10*512 u16
    // (S32 fp32:2, Sb:1, T0b:1, T1b:1, K1..K5 bf16:5)
    long wsElems = (long)(ws_size / 2);
    long chunk = (wsElems - (long)wfix) / (10L * NDIM);
    chunk = (chunk / 128) * 128;
    if (chunk > MDIM) chunk = MDIM;
    if (chunk < 128) chunk = 128;   // min footprint ~3.2 MB

    transpose_k<<<512, 256, 0, stream>>>(Wp, Wpt, 256, 512);
    transpose_k<<<1024, 256, 0, stream>>>(W1, W1t, 512, 512);
    transpose_k<<<1024, 256, 0, stream>>>(W2, W2t, 512, 512);
    transpose_k<<<1024, 256, 0, stream>>>(W3, W3t, 512, 512);

    const double h = 0.1 / 8.0;
    float* OUT = (float*)d_out;   // fp32 output, per reference dtype

    for (long row0 = 0; row0 < MDIM; row0 += chunk) {
        const long rows = (MDIM - row0 < chunk) ? (MDIM - row0) : chunk;
        const size_t CB = (size_t)rows * NDIM;

        u16* base = ws + wfix;
        float* S32 = (float*)base;          // 2*CB u16
        u16* Sb  = base + 2 * CB;
        u16* T0b = base + 3 * CB;
        u16* T1b = base + 4 * CB;
        u16* K1  = base + 5 * CB;
        u16* K2  = base + 6 * CB;
        u16* K3  = base + 7 * CB;
        u16* K4  = base + 8 * CB;
        u16* K5  = base + 9 * CB;
        u16* K6  = K2;                      // k2 dead after stage-6 combo; reuse

        dim3 gg(4, (unsigned)(rows / 128));
        const int NC = (int)(CB / 4 / 256);

        // S = u_t @ Wp + bp + y  -> S32 (fp32) + Sb (bf16); A is fp32 u_t
        gemm_bt<256, 0, true><<<gg, 256, 0, stream>>>(
            (const void*)(u_t + (size_t)row0 * 256), Wpt, bp,
            y + (size_t)row0 * NDIM, Sb, S32);

        auto evalf = [&](const u16* inB, u16* kout) {
            gemm_bt<512, 1, false><<<gg, 256, 0, stream>>>(
                (const void*)inB, W1t, b1, nullptr, T1b, nullptr);
            gemm_bt<512, 1, false><<<gg, 256, 0, stream>>>(
                (const void*)T1b, W2t, b2, nullptr, T0b, nullptr);
            gemm_bt<512, 2, false><<<gg, 256, 0, stream>>>(
                (const void*)T0b, W3t, b3, nullptr, kout, nullptr);
        };

        for (int st = 0; st < 8; ++st) {
            evalf(Sb, K1);
            combo<<<NC, 256, 0, stream>>>(S32, K1, K1, K1, K1, K1,
                (float)(h * 1.0 / 5.0), 0.f, 0.f, 0.f, 0.f, 1, nullptr, T0b);
            evalf(T0b, K2);
            combo<<<NC, 256, 0, stream>>>(S32, K1, K2, K2, K2, K2,
                (float)(h * 3.0 / 40.0), (float)(h * 9.0 / 40.0), 0.f, 0.f, 0.f, 2,
                nullptr, T0b);
            evalf(T0b, K3);
            combo<<<NC, 256, 0, stream>>>(S32, K1, K2, K3, K3, K3,
                (float)(h * 44.0 / 45.0), (float)(h * -56.0 / 15.0),
                (float)(h * 32.0 / 9.0), 0.f, 0.f, 3, nullptr, T0b);
            evalf(T0b, K4);
            combo<<<NC, 256, 0, stream>>>(S32, K1, K2, K3, K4, K4,
                (float)(h * 19372.0 / 6561.0), (float)(h * -25360.0 / 2187.0),
                (float)(h * 64448.0 / 6561.0), (float)(h * -212.0 / 729.0), 0.f, 4,
                nullptr, T0b);
            evalf(T0b, K5);
            combo<<<NC, 256, 0, stream>>>(S32, K1, K2, K3, K4, K5,
                (float)(h * 9017.0 / 3168.0), (float)(h * -355.0 / 33.0),
                (float)(h * 46732.0 / 5247.0), (float)(h * 49.0 / 176.0),
                (float)(h * -5103.0 / 18656.0), 5, nullptr, T0b);
            evalf(T0b, K6);
            // final state update: fp32 into S32 (st<7) or d_out (st==7)
            float* dstF = (st == 7) ? (OUT + (size_t)row0 * NDIM) : S32;
            combo<<<NC, 256, 0, stream>>>(S32, K1, K3, K4, K5, K6,
                (float)(h * 35.0 / 384.0), (float)(h * 500.0 / 1113.0),
                (float)(h * 125.0 / 192.0), (float)(h * -2187.0 / 6784.0),
                (float)(h * 11.0 / 84.0), 5, dstF, Sb);
        }
    }
}